// Round 4
// baseline (317.780 us; speedup 1.0000x reference)
//
#include <hip/hip_runtime.h>
#include <hip/hip_bf16.h>

#define BB 64
#define TT 2048
#define DD 256
#define EPSF 1e-7f
#define ROWS 32                 // rows per chunk
#define CHUNKS 4                // chunks per block
#define BLKROWS (ROWS * CHUNKS) // 128 rows per block
#define XS_STRIDE 264           // shorts/row: 528 B = 33*16 B -> 16B-aligned b128 reads

typedef __attribute__((ext_vector_type(8))) short v8s;   // 8 x bf16 (4 VGPRs) — MFMA A/B frag
typedef __attribute__((ext_vector_type(4))) float v4f;   // MFMA C/D frag

__device__ __forceinline__ float bf2f(unsigned short u) {
    union { unsigned int i; float f; } c;
    c.i = ((unsigned int)u) << 16;
    return c.f;
}

__device__ __forceinline__ unsigned int pack2_bf16(float a, float b) {
    union { __hip_bfloat162 h; unsigned int u; } c;
    c.h = __float22bfloat162_rn(make_float2(a, b));   // v_cvt_pk_bf16_f32, RNE
    return c.u;
}

// exact identity tanh(x) = 1 - 2/(exp(2x)+1)
__device__ __forceinline__ float tanh_fast(float x) {
    float e = __expf(2.0f * x);
    return 1.0f - 2.0f / (e + 1.0f);
}

__device__ __forceinline__ unsigned short f2bf_rn(float f) {
    union { __hip_bfloat16 h; unsigned short u; } c;
    c.h = __float2bfloat16(f);
    return c.u;
}

// ---------------- kernel 1: W[k][n] (fp32) -> Wt in MFMA-FRAGMENT order (bf16) ----------------
// Wt[(((nt*8 + ks)*16 + m)*4 + quad)*8 + j] = bf16(W[k][n]), n = nt*16+m, k = quad*8+ks*32+j.
// For each (nt,ks) the 64 lanes (quad,m) read one CONTIGUOUS 1 KB segment (coalesced).
__global__ __launch_bounds__(256) void pack_wt_frag(const float* __restrict__ W,
                                                    unsigned short* __restrict__ Wt) {
    int idx = blockIdx.x * 256 + threadIdx.x;   // 0..65535
    int j    = idx & 7;
    int quad = (idx >> 3) & 3;
    int m    = (idx >> 5) & 15;
    int ks   = (idx >> 9) & 7;
    int nt   = idx >> 12;
    int n = nt * 16 + m;
    int k = quad * 8 + ks * 32 + j;
    Wt[idx] = f2bf_rn(W[(size_t)k * DD + n]);
}

// ---------------- kernel 2: chunk-persistent fused kernel ------------------------------------
// Block = 128 rows as 4 chunks of 32. Per chunk: pack prefetched x -> LDS(dbuf), barrier,
// e-GEMM (nt-split across 4 waves, B dbuf w/ cyclic wrap), reduce, barrier, p/den/num.
// x for chunk c+1 prefetched into regs during chunk c's compute. num/den accumulate in regs.
__global__ __launch_bounds__(256, 3) void fused_att6(const float* __restrict__ x,
                                                     const unsigned short* __restrict__ Wt,
                                                     const float* __restrict__ bias,
                                                     const float* __restrict__ uw,
                                                     const int* __restrict__ mask,
                                                     float* __restrict__ numpart,
                                                     float* __restrict__ denpart) {
    __shared__ unsigned short xs[2 * ROWS * XS_STRIDE];  // 33792 B double buffer
    __shared__ float ered[4][ROWS];                      // per-wave e partials
    __shared__ float red[4][DD];                         // num merge

    const int tid  = threadIdx.x;
    const int w    = tid >> 6;     // wave 0..3
    const int lane = tid & 63;
    const int quad = lane >> 4;    // 0..3
    const int m    = lane & 15;    // 0..15
    const long B0  = (long)blockIdx.x * BLKROWS;   // block's first row

    // per-lane base into frag-ordered Wt: fragment slot (m*4+quad)*8 shorts
    const size_t blane = (size_t)((m * 4 + quad) * 8);

    // hoisted bias/uw for this wave's nt range (n = (w*4+i)*16 + m) — reused all 4 chunks
    float bias_r[4], uw_r[4];
#pragma unroll
    for (int i = 0; i < 4; ++i) {
        int n = (w * 4 + i) * 16 + m;
        bias_r[i] = bias[n];
        uw_r[i]   = uw[n];
    }

    float num[4] = {0.f, 0.f, 0.f, 0.f};   // accumulated across chunks
    float denacc = 0.f;

    // ---- prologue: issue chunk-0 x loads (regs) and initial B slice (nt = w*4)
    float4 vreg[8];
    {
        const float* gp = x + (B0 + (size_t)w * 8) * DD + lane * 4;
#pragma unroll
        for (int r = 0; r < 8; ++r) vreg[r] = *(const float4*)(gp + (size_t)r * DD);
    }
    v8s bbuf[2][8];
    {
        const unsigned short* bp = Wt + (size_t)(w * 4) * 4096 + blane;
#pragma unroll
        for (int ks = 0; ks < 8; ++ks) bbuf[0][ks] = *(const v8s*)(bp + ks * 512);
    }

    for (int c = 0; c < CHUNKS; ++c) {
        unsigned short* xb = xs + (size_t)(c & 1) * (ROWS * XS_STRIDE);

        // ---- pack prefetched rows into LDS (waits vmcnt via use)
        {
            unsigned short* sp = xb + (size_t)(w * 8) * XS_STRIDE + lane * 4;
#pragma unroll
            for (int r = 0; r < 8; ++r) {
                uint2 pp = make_uint2(pack2_bf16(vreg[r].x, vreg[r].y),
                                      pack2_bf16(vreg[r].z, vreg[r].w));
                *(uint2*)(sp + (size_t)r * XS_STRIDE) = pp;
            }
        }
        // ---- issue next chunk's x loads; they fly during this chunk's compute
        if (c + 1 < CHUNKS) {
            const float* gp = x + (B0 + (size_t)(c + 1) * ROWS + (size_t)w * 8) * DD + lane * 4;
#pragma unroll
            for (int r = 0; r < 8; ++r) vreg[r] = *(const float4*)(gp + (size_t)r * DD);
        }
        __syncthreads();   // barrier 1: xb staged

        // ---- A fragments for block-rows m and m+16 of this chunk
        v8s a0[8], a1[8];
        {
            const unsigned short* ap0 = xb + (size_t)m * XS_STRIDE + quad * 8;
#pragma unroll
            for (int ks = 0; ks < 8; ++ks) {
                a0[ks] = *(const v8s*)(ap0 + ks * 32);
                a1[ks] = *(const v8s*)(ap0 + 16 * XS_STRIDE + ks * 32);
            }
        }

        float esum[2][4];
#pragma unroll
        for (int mt = 0; mt < 2; ++mt)
#pragma unroll
            for (int r = 0; r < 4; ++r) esum[mt][r] = 0.f;

#pragma unroll
        for (int i = 0; i < 4; ++i) {
            const int cur = i & 1;
            // cyclic B prefetch: i<3 -> next nt; i==3 -> wrap to nt0 for next chunk.
            {
                const int nxt = (i < 3) ? (w * 4 + i + 1) : (w * 4);
                const unsigned short* bp = Wt + (size_t)nxt * 4096 + blane;
#pragma unroll
                for (int ks = 0; ks < 8; ++ks) bbuf[cur ^ 1][ks] = *(const v8s*)(bp + ks * 512);
            }
            v4f acc0 = {0.f, 0.f, 0.f, 0.f};
            v4f acc1 = {0.f, 0.f, 0.f, 0.f};
#pragma unroll
            for (int ks = 0; ks < 8; ++ks) {
                acc0 = __builtin_amdgcn_mfma_f32_16x16x32_bf16(a0[ks], bbuf[cur][ks], acc0, 0, 0, 0);
                acc1 = __builtin_amdgcn_mfma_f32_16x16x32_bf16(a1[ks], bbuf[cur][ks], acc1, 0, 0, 0);
            }
#pragma unroll
            for (int r = 0; r < 4; ++r) {
                esum[0][r] += tanh_fast(acc0[r] + bias_r[i]) * uw_r[i];
                esum[1][r] += tanh_fast(acc1[r] + bias_r[i]) * uw_r[i];
            }
        }

        // ---- reduce over 16 n-lanes; m==0 lanes write this wave's e-partials for 32 rows
#pragma unroll
        for (int o = 1; o < 16; o <<= 1)
#pragma unroll
            for (int mt = 0; mt < 2; ++mt)
#pragma unroll
                for (int r = 0; r < 4; ++r)
                    esum[mt][r] += __shfl_xor(esum[mt][r], o, 64);
        if (m == 0) {
#pragma unroll
            for (int mt = 0; mt < 2; ++mt)
#pragma unroll
                for (int r = 0; r < 4; ++r)
                    ered[w][mt * 16 + quad * 4 + r] = esum[mt][r];
        }
        __syncthreads();   // barrier 2: ered ready

        // ---- p for all 32 rows (identical in all waves); den accumulate
        const int rl = lane & 31;
        float et = ered[0][rl] + ered[1][rl] + ered[2][rl] + ered[3][rl];
        float p_loc = __expf(et) * (float)mask[B0 + (size_t)c * ROWS + rl];
        float den = p_loc;
#pragma unroll
        for (int o = 1; o < 32; o <<= 1) den += __shfl_xor(den, o, 64);
        denacc += den;

        float p_all[8];
#pragma unroll
        for (int t = 0; t < 8; ++t) p_all[t] = __shfl(p_loc, w * 8 + t, 64);

        // ---- accumulate weighted sum over own 8 rows from LDS; lane covers d = lane*4..+3
        {
            const unsigned short* xp = xb + (size_t)(w * 8) * XS_STRIDE + lane * 4;
#pragma unroll
            for (int t = 0; t < 8; ++t) {
                uint2 xv = *(const uint2*)(xp + (size_t)t * XS_STRIDE);
                float pt = p_all[t];
                num[0] += pt * bf2f((unsigned short)(xv.x & 0xffffu));
                num[1] += pt * bf2f((unsigned short)(xv.x >> 16));
                num[2] += pt * bf2f((unsigned short)(xv.y & 0xffffu));
                num[3] += pt * bf2f((unsigned short)(xv.y >> 16));
            }
        }
    }

    // ---- epilogue: merge 4 wave-partials once, single store per block
    *(float4*)&red[w][lane * 4] = make_float4(num[0], num[1], num[2], num[3]);
    __syncthreads();
    float s = red[0][tid] + red[1][tid] + red[2][tid] + red[3][tid];
    numpart[(size_t)blockIdx.x * DD + tid] = s;
    if (tid == 0) denpart[blockIdx.x] = denacc;   // wave 0's denacc covers all 128 rows
}

// ---------------- kernel 3: out[b][d] = sum_c num[b*16+c][d] / (sum_c den[b*16+c] + EPS) ------
__global__ __launch_bounds__(256) void finalize(const float* __restrict__ numpart,
                                                const float* __restrict__ denpart,
                                                float* __restrict__ out) {
    __shared__ float4 part[4][64];
    int b = blockIdx.x, t = threadIdx.x;
    int d4 = t & 63;        // float4 index over 256 d
    int cq = t >> 6;        // chunk quarter (4 chunks each)
    float4 s = make_float4(0.f, 0.f, 0.f, 0.f);
    const float* np = numpart + ((size_t)b * 16 + (size_t)cq * 4) * DD + d4 * 4;
#pragma unroll
    for (int c = 0; c < 4; ++c) {
        float4 v = *(const float4*)(np + (size_t)c * DD);
        s.x += v.x; s.y += v.y; s.z += v.z; s.w += v.w;
    }
    part[cq][d4] = s;
    float dp = denpart[b * 16 + (t & 15)];
    __syncthreads();
    if (t < 64) {   // wave 0: each 16-lane group holds all 16 den partials -> reduce within group
#pragma unroll
        for (int o = 1; o < 16; o <<= 1) dp += __shfl_xor(dp, o, 64);
        float4 p0 = part[0][t], p1 = part[1][t], p2 = part[2][t], p3 = part[3][t];
        float inv = 1.0f / (dp + EPSF);
        float4 r;
        r.x = (p0.x + p1.x + p2.x + p3.x) * inv;
        r.y = (p0.y + p1.y + p2.y + p3.y) * inv;
        r.z = (p0.z + p1.z + p2.z + p3.z) * inv;
        r.w = (p0.w + p1.w + p2.w + p3.w) * inv;
        *(float4*)(out + (size_t)b * DD + t * 4) = r;
    }
}

extern "C" void kernel_launch(void* const* d_in, const int* in_sizes, int n_in,
                              void* d_out, int out_size, void* d_ws, size_t ws_size,
                              hipStream_t stream) {
    const float* x    = (const float*)d_in[0];  // [64,2048,256] fp32
    const float* W    = (const float*)d_in[1];  // [256,256] fp32
    const float* bias = (const float*)d_in[2];  // [256] fp32
    const float* uw   = (const float*)d_in[3];  // [256] fp32
    const int*   mask = (const int*)d_in[4];    // [64,2048] int32
    float*       out  = (float*)d_out;          // [64,256] fp32

    char* ws = (char*)d_ws;
    unsigned short* Wt = (unsigned short*)ws;               // 128 KB bf16 W in frag order
    float* numpart     = (float*)(ws + 131072);             // 1024*256*4 = 1 MB
    float* denpart     = (float*)(ws + 131072 + 1048576);   // 4 KB

    pack_wt_frag<<<dim3(256), dim3(256), 0, stream>>>(W, Wt);
    fused_att6<<<dim3(1024), dim3(256), 0, stream>>>(x, Wt, bias, uw, mask, numpart, denpart);
    finalize<<<dim3(64), dim3(256), 0, stream>>>(numpart, denpart, out);
}

// Round 5
// 241.089 us; speedup vs baseline: 1.3181x; 1.3181x over previous
//
#include <hip/hip_runtime.h>
#include <hip/hip_bf16.h>

#define BB 64
#define TT 2048
#define DD 256
#define EPSF 1e-7f
#define WROWS 16        // rows per wave (fully independent waves, no barriers)
#define XS_STRIDE 264   // shorts/row: 528 B = 33*16 B -> 16B-aligned b128 reads

typedef __attribute__((ext_vector_type(8))) short v8s;   // 8 x bf16 (4 VGPRs) — MFMA A/B frag
typedef __attribute__((ext_vector_type(4))) float v4f;   // MFMA C/D frag

__device__ __forceinline__ float bf2f(unsigned short u) {
    union { unsigned int i; float f; } c;
    c.i = ((unsigned int)u) << 16;
    return c.f;
}

__device__ __forceinline__ unsigned int pack2_bf16(float a, float b) {
    union { __hip_bfloat162 h; unsigned int u; } c;
    c.h = __float22bfloat162_rn(make_float2(a, b));   // v_cvt_pk_bf16_f32, RNE
    return c.u;
}

// exact identity tanh(x) = 1 - 2/(exp(2x)+1)
__device__ __forceinline__ float tanh_fast(float x) {
    float e = __expf(2.0f * x);
    return 1.0f - 2.0f / (e + 1.0f);
}

__device__ __forceinline__ unsigned short f2bf_rn(float f) {
    union { __hip_bfloat16 h; unsigned short u; } c;
    c.h = __float2bfloat16(f);
    return c.u;
}

// ---------------- kernel 1: W -> frag-order bf16 Wt, plus (bias,uw) interleave ---------------
// Wt[(((nt*8 + ks)*16 + m)*4 + quad)*8 + j] = bf16(W[k][n]), n = nt*16+m, k = quad*8+ks*32+j.
// For each (nt,ks) the 64 lanes (quad,m) read one CONTIGUOUS 1 KB segment (coalesced).
// buv[n] = (bias[n], uw[n]) so the hot loop does one dwordx2 per nt.
__global__ __launch_bounds__(256) void pack_wt_frag(const float* __restrict__ W,
                                                    const float* __restrict__ bias,
                                                    const float* __restrict__ uw,
                                                    unsigned short* __restrict__ Wt,
                                                    float2* __restrict__ buv) {
    int idx = blockIdx.x * 256 + threadIdx.x;   // 0..65535
    int j    = idx & 7;
    int quad = (idx >> 3) & 3;
    int m    = (idx >> 5) & 15;
    int ks   = (idx >> 9) & 7;
    int nt   = idx >> 12;
    int n = nt * 16 + m;
    int k = quad * 8 + ks * 32 + j;
    Wt[idx] = f2bf_rn(W[(size_t)k * DD + n]);
    if (blockIdx.x == 0) buv[threadIdx.x] = make_float2(bias[threadIdx.x], uw[threadIdx.x]);
}

// ---------------- kernel 2: barrier-free fused kernel, 16 rows per WAVE ----------------------
// Each wave: stage own 16 rows -> own LDS slice (bf16), A-frag in regs (1 m-tile, 32 VGPR),
// loop nt=0..15 {B dbuf prefetch, 8 MFMA, tanh*uw accumulate}, 16-lane reduce, exp/den,
// p distributed via 12 shfl into statically-indexed pg[4][4], num from own LDS, one store.
// NO __syncthreads anywhere; waves are fully independent instruction streams.
__global__ __launch_bounds__(256, 3) void fused_att7(const float* __restrict__ x,
                                                     const unsigned short* __restrict__ Wt,
                                                     const float2* __restrict__ buv,
                                                     const int* __restrict__ mask,
                                                     float* __restrict__ numpart,
                                                     float* __restrict__ denpart) {
    __shared__ unsigned short xs[4 * WROWS * XS_STRIDE];  // 33792 B, per-wave private slices

    const int tid  = threadIdx.x;
    const int w    = tid >> 6;     // wave 0..3
    const int lane = tid & 63;
    const int quad = lane >> 4;    // 0..3
    const int m    = lane & 15;    // 0..15
    const int wid  = blockIdx.x * 4 + w;          // global wave id, 0..8191
    const long Rw0 = (long)wid * WROWS;           // this wave's first row

    unsigned short* slice = xs + (size_t)(w * WROWS) * XS_STRIDE;

    // per-lane base into frag-ordered Wt: fragment slot (m*4+quad)*8 shorts
    const unsigned short* wbase = Wt + (size_t)((m * 4 + quad) * 8);

    // ---- stage own 16 rows (two 8-row batches to bound transient VGPRs); issue B0 early
    v8s bbuf[2][8];
    {
        const float* gp = x + Rw0 * DD + lane * 4;
        unsigned short* sp = slice + lane * 4;
        float4 vr[8];
#pragma unroll
        for (int r = 0; r < 8; ++r) vr[r] = *(const float4*)(gp + (size_t)r * DD);
        // issue first B slice (nt=0) while batch-1 x loads are in flight
#pragma unroll
        for (int ks = 0; ks < 8; ++ks) bbuf[0][ks] = *(const v8s*)(wbase + ks * 512);
#pragma unroll
        for (int r = 0; r < 8; ++r) {
            uint2 pp = make_uint2(pack2_bf16(vr[r].x, vr[r].y), pack2_bf16(vr[r].z, vr[r].w));
            *(uint2*)(sp + (size_t)r * XS_STRIDE) = pp;
        }
#pragma unroll
        for (int r = 0; r < 8; ++r) vr[r] = *(const float4*)(gp + (size_t)(8 + r) * DD);
#pragma unroll
        for (int r = 0; r < 8; ++r) {
            uint2 pp = make_uint2(pack2_bf16(vr[r].x, vr[r].y), pack2_bf16(vr[r].z, vr[r].w));
            *(uint2*)(sp + (size_t)(8 + r) * XS_STRIDE) = pp;
        }
    }

    // ---- A fragments for own 16 rows (lane reads slice row m) — 8 x ds_read_b128
    v8s a0[8];
    {
        const unsigned short* ap0 = slice + (size_t)m * XS_STRIDE + quad * 8;
#pragma unroll
        for (int ks = 0; ks < 8; ++ks) a0[ks] = *(const v8s*)(ap0 + ks * 32);
    }

    // ---- nt loop over all 256 output cols: 8 MFMA + tanh*uw accumulate per nt, B dbuf
    float psum[4] = {0.f, 0.f, 0.f, 0.f};
#pragma unroll
    for (int i = 0; i < 16; ++i) {
        const int cur = i & 1;
        if (i < 15) {   // prefetch next nt's B (coalesced 1 KB loads, L2/L3-resident)
            const unsigned short* bp = wbase + (size_t)(i + 1) * 4096;
#pragma unroll
            for (int ks = 0; ks < 8; ++ks) bbuf[cur ^ 1][ks] = *(const v8s*)(bp + ks * 512);
        }
        float2 bu = buv[i * 16 + m];   // (bias, uw) for n = i*16+m; 128 B segment, L1 hit
        v4f acc = {0.f, 0.f, 0.f, 0.f};
#pragma unroll
        for (int ks = 0; ks < 8; ++ks)
            acc = __builtin_amdgcn_mfma_f32_16x16x32_bf16(a0[ks], bbuf[cur][ks], acc, 0, 0, 0);
#pragma unroll
        for (int r = 0; r < 4; ++r)
            psum[r] += tanh_fast(acc[r] + bu.x) * bu.y;
    }

    // ---- reduce over the 16 n-lanes (m dim): e complete for own quad's 4 rows
#pragma unroll
    for (int o = 1; o < 16; o <<= 1)
#pragma unroll
        for (int r = 0; r < 4; ++r)
            psum[r] += __shfl_xor(psum[r], o, 64);

    // ---- p for own quad's rows; den over all 16 rows
    float p_own[4];
#pragma unroll
    for (int r = 0; r < 4; ++r)
        p_own[r] = __expf(psum[r]) * (float)mask[Rw0 + quad * 4 + r];
    float den = p_own[0] + p_own[1] + p_own[2] + p_own[3];
    den += __shfl_xor(den, 16, 64);
    den += __shfl_xor(den, 32, 64);

    // ---- distribute p statically: pg[g][r] = p of row (quad^g)*4+r
    float pg[4][4];
#pragma unroll
    for (int r = 0; r < 4; ++r) {
        pg[0][r] = p_own[r];
        pg[1][r] = __shfl_xor(p_own[r], 16, 64);
        pg[2][r] = __shfl_xor(p_own[r], 32, 64);
        pg[3][r] = __shfl_xor(p_own[r], 48, 64);
    }

    // ---- weighted sum over own 16 rows from own LDS slice, lane covers d = lane*4..+3.
    // Row order is lane-local ((quad^g)*4+r) — sum over rows is order-invariant.
    float num[4] = {0.f, 0.f, 0.f, 0.f};
    {
        const unsigned short* xp = slice + lane * 4;
#pragma unroll
        for (int g = 0; g < 4; ++g) {
            const int rq = quad ^ g;
#pragma unroll
            for (int r = 0; r < 4; ++r) {
                uint2 xv = *(const uint2*)(xp + (size_t)(rq * 4 + r) * XS_STRIDE);
                float pt = pg[g][r];
                num[0] += pt * bf2f((unsigned short)(xv.x & 0xffffu));
                num[1] += pt * bf2f((unsigned short)(xv.x >> 16));
                num[2] += pt * bf2f((unsigned short)(xv.y & 0xffffu));
                num[3] += pt * bf2f((unsigned short)(xv.y >> 16));
            }
        }
    }

    // ---- one coalesced 1 KB store per wave; lane 0 writes den
    *(float4*)(numpart + (size_t)wid * DD + lane * 4) = make_float4(num[0], num[1], num[2], num[3]);
    if (lane == 0) denpart[wid] = den;
}

// ---------------- kernel 3: out[b][d] = sum_c num[b*128+c][d] / (sum_c den[b*128+c] + EPS) ----
__global__ __launch_bounds__(256) void finalize(const float* __restrict__ numpart,
                                                const float* __restrict__ denpart,
                                                float* __restrict__ out) {
    __shared__ float4 part[4][64];
    int b = blockIdx.x, t = threadIdx.x;
    int d4 = t & 63;        // float4 index over 256 d
    int cq = t >> 6;        // chunk quarter (32 chunks each)
    float4 s = make_float4(0.f, 0.f, 0.f, 0.f);
    const float* np = numpart + ((size_t)b * 128 + (size_t)cq * 32) * DD + d4 * 4;
#pragma unroll
    for (int c = 0; c < 32; ++c) {
        float4 v = *(const float4*)(np + (size_t)c * DD);
        s.x += v.x; s.y += v.y; s.z += v.z; s.w += v.w;
    }
    part[cq][d4] = s;
    __syncthreads();
    if (t < 64) {   // wave 0: reduce 128 dens (2 per lane), merge 4 quarters, store
        float dp = denpart[b * 128 + t] + denpart[b * 128 + 64 + t];
#pragma unroll
        for (int o = 1; o < 64; o <<= 1) dp += __shfl_xor(dp, o, 64);
        float4 p0 = part[0][t], p1 = part[1][t], p2 = part[2][t], p3 = part[3][t];
        float inv = 1.0f / (dp + EPSF);
        float4 r;
        r.x = (p0.x + p1.x + p2.x + p3.x) * inv;
        r.y = (p0.y + p1.y + p2.y + p3.y) * inv;
        r.z = (p0.z + p1.z + p2.z + p3.z) * inv;
        r.w = (p0.w + p1.w + p2.w + p3.w) * inv;
        *(float4*)(out + (size_t)b * DD + t * 4) = r;
    }
}

extern "C" void kernel_launch(void* const* d_in, const int* in_sizes, int n_in,
                              void* d_out, int out_size, void* d_ws, size_t ws_size,
                              hipStream_t stream) {
    const float* x    = (const float*)d_in[0];  // [64,2048,256] fp32
    const float* W    = (const float*)d_in[1];  // [256,256] fp32
    const float* bias = (const float*)d_in[2];  // [256] fp32
    const float* uw   = (const float*)d_in[3];  // [256] fp32
    const int*   mask = (const int*)d_in[4];    // [64,2048] int32
    float*       out  = (float*)d_out;          // [64,256] fp32

    char* ws = (char*)d_ws;
    unsigned short* Wt = (unsigned short*)ws;                 // 128 KB bf16 W in frag order
    float2* buv        = (float2*)(ws + 131072);              // 2 KB (bias,uw) pairs
    float* numpart     = (float*)(ws + 131072 + 2048);        // 8192*256*4 = 8 MB
    float* denpart     = (float*)(ws + 131072 + 2048 + 8388608); // 32 KB

    pack_wt_frag<<<dim3(256), dim3(256), 0, stream>>>(W, bias, uw, Wt, buv);
    fused_att7<<<dim3(2048), dim3(256), 0, stream>>>(x, Wt, buv, mask, numpart, denpart);
    finalize<<<dim3(64), dim3(256), 0, stream>>>(numpart, denpart, out);
}